// Round 1
// baseline (7031.044 us; speedup 1.0000x reference)
//
#include <hip/hip_runtime.h>
#include <hip/hip_bf16.h>

#define BATCH 64
#define IN_SIZE 4096
#define IN_DIM 128
#define HEADS 2
#define OUT_SIZE 128
#define NPAIR (BATCH*HEADS)
#define INV_EPS 10.0f
#define MAX_ITER 50
#define A_MARG (1.0f/32.0f)

typedef unsigned int u32;

__device__ __forceinline__ float bflo(u32 kk){ return __uint_as_float(kk<<16); }
__device__ __forceinline__ float bfhi(u32 kk){ return __uint_as_float(kk & 0xffff0000u); }

// ---------------------------------------------------------------------------
// Kernel 1: Kb[p][i][o] = bf16( exp( (x[n] . w[m][o]) / eps ) )
// block: 256 thr, tile 128 rows x 128 cols, pair = blockIdx.y
// ---------------------------------------------------------------------------
__global__ __launch_bounds__(256) void kgen(const float* __restrict__ x,
                                            const float* __restrict__ w,
                                            __hip_bfloat16* __restrict__ Kb)
{
    const int pair = blockIdx.y;
    const int n = pair >> 1, m = pair & 1;
    const int r0 = blockIdx.x * 128;

    __shared__ float xs[128][128];
    __shared__ float ws[128][129];   // ws[d][o], pad 129 -> conflict-free both ways

    {   // stage x rows (coalesced float4)
        const float4* src = (const float4*)(x + ((size_t)n*IN_SIZE + r0)*IN_DIM);
        float4* dst = (float4*)(&xs[0][0]);
        for (int t = threadIdx.x; t < 128*128/4; t += 256) dst[t] = src[t];
    }
    {   // stage w[m] transposed (coalesced read, conflict-free LDS write via pad)
        const float* src = w + (size_t)m*OUT_SIZE*IN_DIM;
        for (int t = threadIdx.x; t < OUT_SIZE*IN_DIM; t += 256) {
            int o = t >> 7, d = t & 127;
            ws[d][o] = src[t];
        }
    }
    __syncthreads();

    const int oq = threadIdx.x & 31;   // o lane-stride 1 -> conflict-free ws reads
    const int rq = threadIdx.x >> 5;   // 0..7, 16 rows each

    float acc[16][4];
    #pragma unroll
    for (int ri=0;ri<16;++ri)
        #pragma unroll
        for (int oi=0;oi<4;++oi) acc[ri][oi]=0.f;

    for (int d = 0; d < 128; ++d) {
        float wv[4];
        #pragma unroll
        for (int oi=0;oi<4;++oi) wv[oi] = ws[d][oq + 32*oi];
        float xv[16];
        #pragma unroll
        for (int ri=0;ri<16;++ri) xv[ri] = xs[rq*16+ri][d];
        #pragma unroll
        for (int ri=0;ri<16;++ri)
            #pragma unroll
            for (int oi=0;oi<4;++oi)
                acc[ri][oi] = fmaf(xv[ri], wv[oi], acc[ri][oi]);
    }

    __hip_bfloat16* out = Kb + (size_t)pair*IN_SIZE*OUT_SIZE + (size_t)r0*OUT_SIZE;
    #pragma unroll
    for (int ri=0;ri<16;++ri) {
        int r = rq*16+ri;
        #pragma unroll
        for (int oi=0;oi<4;++oi) {
            int o = oq + 32*oi;
            out[(size_t)r*OUT_SIZE + o] = __float2bfloat16(__expf(INV_EPS * acc[ri][oi]));
        }
    }
}

// ---------------------------------------------------------------------------
// Kernel 2: Sinkhorn, 50 fused iterations. One block (1024 thr) per pair.
// Lane l owns columns (2l, 2l+1); v kept in registers; one K read per iter.
// ---------------------------------------------------------------------------
__global__ __launch_bounds__(1024) void sinkhorn(const __hip_bfloat16* __restrict__ Kb,
                                                 float* __restrict__ uo,
                                                 float* __restrict__ vo)
{
    const int pair = blockIdx.x;
    const u32* Kp = (const u32*)(Kb + (size_t)pair*IN_SIZE*OUT_SIZE); // row = 64 u32
    const int tid  = threadIdx.x;
    const int wave = tid >> 6;   // 16 waves, 256 rows each
    const int lane = tid & 63;

    __shared__ float red[16][128];
    __shared__ float vnew[128];

    float v0 = 1.f, v1 = 1.f;

    for (int it = 0; it < MAX_ITER; ++it) {
        const bool last = (it == MAX_ITER-1);
        float acc0 = 0.f, acc1 = 0.f;
        const u32* rp = Kp + (size_t)wave*256*64 + lane;
        for (int r = 0; r < 256; ++r) {
            u32 kk = rp[(size_t)r*64];
            float k0 = bflo(kk), k1 = bfhi(kk);
            float p = fmaf(k0, v0, k1*v1);
            p += __shfl_xor(p, 1, 64);
            p += __shfl_xor(p, 2, 64);
            p += __shfl_xor(p, 4, 64);
            p += __shfl_xor(p, 8, 64);
            p += __shfl_xor(p, 16, 64);
            p += __shfl_xor(p, 32, 64);
            float ui = A_MARG * __builtin_amdgcn_rcpf(p);
            acc0 = fmaf(ui, k0, acc0);
            acc1 = fmaf(ui, k1, acc1);
            if (last && lane == 0) uo[(size_t)pair*IN_SIZE + wave*256 + r] = ui;
        }
        *(float2*)&red[wave][2*lane] = make_float2(acc0, acc1);
        __syncthreads();
        if (tid < 128) {
            float s = 0.f;
            #pragma unroll
            for (int wv_ = 0; wv_ < 16; ++wv_) s += red[wv_][tid];
            float vv = __builtin_amdgcn_rcpf(s);
            vnew[tid] = vv;
            if (last) vo[(size_t)pair*OUT_SIZE + tid] = vv;
        }
        __syncthreads();
        float2 vv2 = *(float2*)&vnew[2*lane];
        v0 = vv2.x; v1 = vv2.y;
        // next write to red happens after the (long) row loop of the next
        // iteration; red was last read before the 2nd barrier -> safe.
        __syncthreads();
    }
}

// ---------------------------------------------------------------------------
// Kernel 3: out[n][o][m][d] = v_o * sum_i (u_i K[i][o]) x[i][d]
// block: 256 thr, one pair x one 64-wide d-half; i tiled by 64 through LDS.
// ---------------------------------------------------------------------------
__global__ __launch_bounds__(256) void outgemm(const __hip_bfloat16* __restrict__ Kb,
                                               const float* __restrict__ uo,
                                               const float* __restrict__ vo,
                                               const float* __restrict__ x,
                                               float* __restrict__ out)
{
    const int dh = blockIdx.x;      // 0..1
    const int pair = blockIdx.y;
    const int n = pair >> 1, m = pair & 1;
    const int tid = threadIdx.x;
    const int og = tid >> 3;        // 0..31
    const int dg = tid & 7;         // 0..7

    __shared__ float ts[64][128];   // u_i * K[i][o]
    __shared__ float xsd[64][64];   // x[i][dh*64 + d]

    float acc[4][8];
    #pragma unroll
    for (int oi=0;oi<4;++oi)
        #pragma unroll
        for (int j=0;j<8;++j) acc[oi][j]=0.f;

    for (int t0 = 0; t0 < IN_SIZE; t0 += 64) {
        {   // stage u_i * K
            const u32* src = (const u32*)(Kb + ((size_t)pair*IN_SIZE + t0)*OUT_SIZE);
            for (int t = tid; t < 4096; t += 256) {
                int row = t >> 6, c2 = t & 63;
                u32 kk = src[t];
                float uu = uo[(size_t)pair*IN_SIZE + t0 + row];
                *(float2*)&ts[row][2*c2] = make_float2(bflo(kk)*uu, bfhi(kk)*uu);
            }
        }
        {   // stage x d-half
            const float* xb = x + ((size_t)n*IN_SIZE + t0)*IN_DIM + dh*64;
            for (int t = tid; t < 1024; t += 256) {
                int row = t >> 4, c4 = t & 15;
                *(float4*)&xsd[row][c4*4] = *(const float4*)&xb[(size_t)row*IN_DIM + c4*4];
            }
        }
        __syncthreads();
        for (int i = 0; i < 64; ++i) {
            float tv[4];
            #pragma unroll
            for (int oi=0;oi<4;++oi) tv[oi] = ts[i][og + 32*oi];
            float4 xa  = *(float4*)&xsd[i][dg*8];
            float4 xb4 = *(float4*)&xsd[i][dg*8+4];
            float xv[8] = {xa.x,xa.y,xa.z,xa.w,xb4.x,xb4.y,xb4.z,xb4.w};
            #pragma unroll
            for (int oi=0;oi<4;++oi)
                #pragma unroll
                for (int j=0;j<8;++j)
                    acc[oi][j] = fmaf(tv[oi], xv[j], acc[oi][j]);
        }
        __syncthreads();
    }

    #pragma unroll
    for (int oi=0;oi<4;++oi) {
        int o = og + 32*oi;
        float vv = vo[(size_t)pair*OUT_SIZE + o];
        size_t base = (((size_t)n*OUT_SIZE + o)*HEADS + m)*IN_DIM + (size_t)dh*64 + dg*8;
        float4 s0 = make_float4(acc[oi][0]*vv, acc[oi][1]*vv, acc[oi][2]*vv, acc[oi][3]*vv);
        float4 s1 = make_float4(acc[oi][4]*vv, acc[oi][5]*vv, acc[oi][6]*vv, acc[oi][7]*vv);
        *(float4*)&out[base]   = s0;
        *(float4*)&out[base+4] = s1;
    }
}

// ---------------------------------------------------------------------------
extern "C" void kernel_launch(void* const* d_in, const int* in_sizes, int n_in,
                              void* d_out, int out_size, void* d_ws, size_t ws_size,
                              hipStream_t stream)
{
    const float* x = (const float*)d_in[0];
    const float* w = (const float*)d_in[1];
    float* out = (float*)d_out;

    char* ws = (char*)d_ws;
    __hip_bfloat16* Kb = (__hip_bfloat16*)ws;                       // 134,217,728 B
    float* uo = (float*)(ws + (size_t)NPAIR*IN_SIZE*OUT_SIZE*2);    // 2,097,152 B
    float* vo = uo + (size_t)NPAIR*IN_SIZE;                         // 65,536 B

    kgen    <<<dim3(IN_SIZE/128, NPAIR), 256,  0, stream>>>(x, w, Kb);
    sinkhorn<<<dim3(NPAIR),              1024, 0, stream>>>(Kb, uo, vo);
    outgemm <<<dim3(2, NPAIR),           256,  0, stream>>>(Kb, uo, vo, x, out);
}

// Round 2
// 1944.545 us; speedup vs baseline: 3.6158x; 3.6158x over previous
//
#include <hip/hip_runtime.h>
#include <hip/hip_bf16.h>

#define BATCH 64
#define IN_SIZE 4096
#define IN_DIM 128
#define HEADS 2
#define OUT_SIZE 128
#define NPAIR (BATCH*HEADS)
#define INV_EPS 10.0f
#define MAX_ITER 50
#define A_MARG (1.0f/32.0f)

typedef unsigned int u32;

__device__ __forceinline__ float bflo(u32 kk){ return __uint_as_float(kk<<16); }
__device__ __forceinline__ float bfhi(u32 kk){ return __uint_as_float(kk & 0xffff0000u); }

// DPP add: x + perm<CTRL>(x). All-VALU cross-lane (16-lane row scope).
template<int CTRL>
__device__ __forceinline__ float dpp_add(float x) {
    int yi = __builtin_amdgcn_update_dpp(0, __float_as_int(x), CTRL, 0xf, 0xf, false);
    return x + __int_as_float(yi);
}

// ---------------------------------------------------------------------------
// Kernel 1: Kb[p][i][o] = bf16( exp( (x[n] . w[m][o]) / eps ) )
// ---------------------------------------------------------------------------
__global__ __launch_bounds__(256) void kgen(const float* __restrict__ x,
                                            const float* __restrict__ w,
                                            __hip_bfloat16* __restrict__ Kb)
{
    const int pair = blockIdx.y;
    const int n = pair >> 1, m = pair & 1;
    const int r0 = blockIdx.x * 128;

    __shared__ float xs[128][128];
    __shared__ float ws[128][129];

    {
        const float4* src = (const float4*)(x + ((size_t)n*IN_SIZE + r0)*IN_DIM);
        float4* dst = (float4*)(&xs[0][0]);
        for (int t = threadIdx.x; t < 128*128/4; t += 256) dst[t] = src[t];
    }
    {
        const float* src = w + (size_t)m*OUT_SIZE*IN_DIM;
        for (int t = threadIdx.x; t < OUT_SIZE*IN_DIM; t += 256) {
            int o = t >> 7, d = t & 127;
            ws[d][o] = src[t];
        }
    }
    __syncthreads();

    const int oq = threadIdx.x & 31;
    const int rq = threadIdx.x >> 5;

    float acc[16][4];
    #pragma unroll
    for (int ri=0;ri<16;++ri)
        #pragma unroll
        for (int oi=0;oi<4;++oi) acc[ri][oi]=0.f;

    for (int d = 0; d < 128; ++d) {
        float wv[4];
        #pragma unroll
        for (int oi=0;oi<4;++oi) wv[oi] = ws[d][oq + 32*oi];
        float xv[16];
        #pragma unroll
        for (int ri=0;ri<16;++ri) xv[ri] = xs[rq*16+ri][d];
        #pragma unroll
        for (int ri=0;ri<16;++ri)
            #pragma unroll
            for (int oi=0;oi<4;++oi)
                acc[ri][oi] = fmaf(xv[ri], wv[oi], acc[ri][oi]);
    }

    __hip_bfloat16* out = Kb + (size_t)pair*IN_SIZE*OUT_SIZE + (size_t)r0*OUT_SIZE;
    #pragma unroll
    for (int ri=0;ri<16;++ri) {
        int r = rq*16+ri;
        #pragma unroll
        for (int oi=0;oi<4;++oi) {
            int o = oq + 32*oi;
            out[(size_t)r*OUT_SIZE + o] = __float2bfloat16(__expf(INV_EPS * acc[ri][oi]));
        }
    }
}

// ---------------------------------------------------------------------------
// Kernel 2: Sinkhorn, 50 fused iterations. One block (1024 thr) per pair.
// Each 16-lane group owns one row per step (8 cols/lane, dwordx4 load).
// Row-sum via 4 DPP adds (pure VALU). Colsum xor16/32 once per iteration.
// ---------------------------------------------------------------------------
__global__ __launch_bounds__(1024) void sinkhorn(const __hip_bfloat16* __restrict__ Kb,
                                                 float* __restrict__ uo,
                                                 float* __restrict__ vo)
{
    const int pair = blockIdx.x;
    const int tid  = threadIdx.x;
    const int wave = tid >> 6;      // 16 waves, 256 rows each
    const int lane = tid & 63;
    const int grp  = lane >> 4;     // 0..3  (row within 4-row step)
    const int s    = lane & 15;     // 0..15 (column slice: 8s..8s+7)

    __shared__ float red[16][128];
    __shared__ float vnew[128];

    // int4 granularity: one row = 128 cols * 2B = 16 int4
    const int4* gp = (const int4*)(Kb + (size_t)pair*IN_SIZE*OUT_SIZE)
                   + (size_t)wave*256*16 + (size_t)grp*16 + s;
    // step g covers rows wave*256 + g*4 + grp; stride per g: 4 rows = 64 int4

    float v[8];
    #pragma unroll
    for (int j=0;j<8;++j) v[j] = 1.f;

    for (int it = 0; it < MAX_ITER; ++it) {
        const bool last = (it == MAX_ITER-1);
        float acc[8];
        #pragma unroll
        for (int j=0;j<8;++j) acc[j] = 0.f;

        int4 cur = gp[0];
        int4 nx1 = gp[64];
        for (int g = 0; g < 64; ++g) {
            int4 nx2 = gp[(size_t)(((g+2)&63))*64];
            // unpack 8 bf16 -> f32
            float k[8];
            k[0]=bflo(cur.x); k[1]=bfhi(cur.x);
            k[2]=bflo(cur.y); k[3]=bfhi(cur.y);
            k[4]=bflo(cur.z); k[5]=bfhi(cur.z);
            k[6]=bflo(cur.w); k[7]=bfhi(cur.w);
            // row dot: per-lane partial over 8 cols
            float p = k[0]*v[0];
            #pragma unroll
            for (int j=1;j<8;++j) p = fmaf(k[j], v[j], p);
            // 16-lane sum via DPP (quad xor1, quad xor2, half-mirror, mirror)
            p = dpp_add<0xB1>(p);
            p = dpp_add<0x4E>(p);
            p = dpp_add<0x141>(p);
            p = dpp_add<0x140>(p);
            float ui = A_MARG * __builtin_amdgcn_rcpf(p);
            #pragma unroll
            for (int j=0;j<8;++j) acc[j] = fmaf(ui, k[j], acc[j]);
            if (last && s == 0)
                uo[(size_t)pair*IN_SIZE + wave*256 + g*4 + grp] = ui;
            cur = nx1; nx1 = nx2;
        }
        // reduce colsums across the 4 groups (same s => same columns)
        #pragma unroll
        for (int j=0;j<8;++j) {
            acc[j] += __shfl_xor(acc[j], 16, 64);
            acc[j] += __shfl_xor(acc[j], 32, 64);
        }
        if (lane < 16) {
            *(float4*)&red[wave][8*s]   = make_float4(acc[0],acc[1],acc[2],acc[3]);
            *(float4*)&red[wave][8*s+4] = make_float4(acc[4],acc[5],acc[6],acc[7]);
        }
        __syncthreads();
        if (tid < 128) {
            float sum = 0.f;
            #pragma unroll
            for (int w_ = 0; w_ < 16; ++w_) sum += red[w_][tid];
            float vv = __builtin_amdgcn_rcpf(sum);
            vnew[tid] = vv;
            if (last) vo[(size_t)pair*OUT_SIZE + tid] = vv;
        }
        __syncthreads();
        float4 va = *(const float4*)&vnew[8*s];
        float4 vb = *(const float4*)&vnew[8*s+4];
        v[0]=va.x; v[1]=va.y; v[2]=va.z; v[3]=va.w;
        v[4]=vb.x; v[5]=vb.y; v[6]=vb.z; v[7]=vb.w;
    }
}

// ---------------------------------------------------------------------------
// Kernel 3: out[n][o][m][d] = v_o * sum_i (u_i K[i][o]) x[i][d]
// ---------------------------------------------------------------------------
__global__ __launch_bounds__(256) void outgemm(const __hip_bfloat16* __restrict__ Kb,
                                               const float* __restrict__ uo,
                                               const float* __restrict__ vo,
                                               const float* __restrict__ x,
                                               float* __restrict__ out)
{
    const int dh = blockIdx.x;
    const int pair = blockIdx.y;
    const int n = pair >> 1, m = pair & 1;
    const int tid = threadIdx.x;
    const int og = tid >> 3;
    const int dg = tid & 7;

    __shared__ float ts[64][128];
    __shared__ float xsd[64][64];

    float acc[4][8];
    #pragma unroll
    for (int oi=0;oi<4;++oi)
        #pragma unroll
        for (int j=0;j<8;++j) acc[oi][j]=0.f;

    for (int t0 = 0; t0 < IN_SIZE; t0 += 64) {
        {
            const u32* src = (const u32*)(Kb + ((size_t)pair*IN_SIZE + t0)*OUT_SIZE);
            for (int t = tid; t < 4096; t += 256) {
                int row = t >> 6, c2 = t & 63;
                u32 kk = src[t];
                float uu = uo[(size_t)pair*IN_SIZE + t0 + row];
                *(float2*)&ts[row][2*c2] = make_float2(bflo(kk)*uu, bfhi(kk)*uu);
            }
        }
        {
            const float* xb = x + ((size_t)n*IN_SIZE + t0)*IN_DIM + dh*64;
            for (int t = tid; t < 1024; t += 256) {
                int row = t >> 4, c4 = t & 15;
                *(float4*)&xsd[row][c4*4] = *(const float4*)&xb[(size_t)row*IN_DIM + c4*4];
            }
        }
        __syncthreads();
        for (int i = 0; i < 64; ++i) {
            float tv[4];
            #pragma unroll
            for (int oi=0;oi<4;++oi) tv[oi] = ts[i][og + 32*oi];
            float4 xa  = *(float4*)&xsd[i][dg*8];
            float4 xb4 = *(float4*)&xsd[i][dg*8+4];
            float xv[8] = {xa.x,xa.y,xa.z,xa.w,xb4.x,xb4.y,xb4.z,xb4.w};
            #pragma unroll
            for (int oi=0;oi<4;++oi)
                #pragma unroll
                for (int j=0;j<8;++j)
                    acc[oi][j] = fmaf(tv[oi], xv[j], acc[oi][j]);
        }
        __syncthreads();
    }

    #pragma unroll
    for (int oi=0;oi<4;++oi) {
        int o = og + 32*oi;
        float vv = vo[(size_t)pair*OUT_SIZE + o];
        size_t base = (((size_t)n*OUT_SIZE + o)*HEADS + m)*IN_DIM + (size_t)dh*64 + dg*8;
        float4 s0 = make_float4(acc[oi][0]*vv, acc[oi][1]*vv, acc[oi][2]*vv, acc[oi][3]*vv);
        float4 s1 = make_float4(acc[oi][4]*vv, acc[oi][5]*vv, acc[oi][6]*vv, acc[oi][7]*vv);
        *(float4*)&out[base]   = s0;
        *(float4*)&out[base+4] = s1;
    }
}

// ---------------------------------------------------------------------------
extern "C" void kernel_launch(void* const* d_in, const int* in_sizes, int n_in,
                              void* d_out, int out_size, void* d_ws, size_t ws_size,
                              hipStream_t stream)
{
    const float* x = (const float*)d_in[0];
    const float* w = (const float*)d_in[1];
    float* out = (float*)d_out;

    char* ws = (char*)d_ws;
    __hip_bfloat16* Kb = (__hip_bfloat16*)ws;
    float* uo = (float*)(ws + (size_t)NPAIR*IN_SIZE*OUT_SIZE*2);
    float* vo = uo + (size_t)NPAIR*IN_SIZE;

    kgen    <<<dim3(IN_SIZE/128, NPAIR), 256,  0, stream>>>(x, w, Kb);
    sinkhorn<<<dim3(NPAIR),              1024, 0, stream>>>(Kb, uo, vo);
    outgemm <<<dim3(2, NPAIR),           256,  0, stream>>>(Kb, uo, vo, x, out);
}